// Round 9
// baseline (324.876 us; speedup 1.0000x reference)
//
#include <hip/hip_runtime.h>
#include <hip/hip_cooperative_groups.h>
#include <stdint.h>

namespace cg = cooperative_groups;

// ============================================================================
// MoE collapses exactly to: out = relu(x @ w1) @ w2   (round-0 analysis)
//   - shared expert weights => both top-2 slots compute identical f(x[s])
//   - g1+g2 normalized to 1 => combine gather returns f(x[s])
//   - capacity = S and count1+count2 <= S => no token dropped
// Wg is unused.
//
// Round-8 -> 9: r8's per-phase barriers were neutral; GEMM loop reverts to
// r7 verbatim (the keeper). The remaining cost is non-GEMM wall-clock
// (prep + reduce + 5 launch boundaries ~ 25us). This round: ONE cooperative
// kernel, grid 256 x 512thr x 144KB LDS (exactly 1 block/CU, co-resident):
//   phase A: prep (x->bf16, w1/w2 vectorized 64x64 transposes)
//   phase B: GEMM1 = r7 loop (3-buf, counted vmcnt(6), T1/T2/T5)
//   phase C: GEMM2 = r7 loop, split-K=4 (z0 -> fp32 out, z1..3 -> bf16 pb)
//   phase D: uniform 256-block reduce: out += pb0+pb1+pb2
// Cross-phase reads are single-writer -> first-touch-reader; visibility via
// __threadfence() + grid.sync() (agent-scope fences). pb placed in a
// never-before-read ws region when ws_size allows (extra safety vs stale L2).
// ============================================================================

typedef __attribute__((ext_vector_type(4))) float f32x4;
typedef __attribute__((ext_vector_type(16))) float f32x16;
typedef __attribute__((ext_vector_type(8))) short bf16x8;

#define GPTR(p) (const __attribute__((address_space(1))) void*)(p)
#define LPTR(p) (__attribute__((address_space(3))) void*)(p)

__device__ __forceinline__ ushort f2bf(float f) {
  uint32_t u = __float_as_uint(f);
  uint32_t r = (u + 0x7FFFu + ((u >> 16) & 1u)) >> 16;  // RNE
  return (ushort)r;
}
__device__ __forceinline__ float bf2f(ushort u) {
  return __uint_as_float((uint32_t)u << 16);
}

// ---- r7 GEMM body (verbatim structure; As/Bs passed by reference) -----------
// MODE 1: C0 = relu(A@Bt^T) as bf16.  MODE 2: split-K; bz==0 -> fp32 C0,
// bz>0 -> bf16 partial C1 + (bz-1)*M*N.
// BM=128 x BN=256 x BK=64, 8 waves (2x4), per-wave 64x64 (2x2 32x32 frags).
// 3-buffer LDS, depth-2 prefetch, steady-state s_waitcnt vmcnt(6), ONE
// barrier per K-step; K-step = 4 k-slices software-pipelined (read s+1 while
// MFMA s; 2 staging loads spread into each of slices 0..2).
template <int MODE>
__device__ void gemm_body(const ushort* __restrict__ A,
                          const ushort* __restrict__ Bt,
                          void* __restrict__ C0, ushort* __restrict__ C1,
                          int M, int N, int Ks, int Ktot, int ncx, int cpz,
                          ushort (&As)[3][128 * 64], ushort (&Bs)[3][256 * 64]) {
  constexpr int BK = 64;
  const int tid = threadIdx.x;
  const int lane = tid & 63, wid = tid >> 6;  // 8 waves
  const int wr = wid >> 2, wc = wid & 3;      // 2 x 4 wave grid

  // T1 (2D-chunked): chunk (=XCD) = blockIdx.x & 7, 32 blocks/chunk.
  const int ck = blockIdx.x & 7;
  const int w = blockIdx.x >> 3;
  const int bz = ck / cpz;
  const int rem = ck % cpz;
  const int bx = (rem % ncx) * 4 + (w & 3);
  const int by = (rem / ncx) * 8 + (w >> 2);
  const int row0 = by * 128, col0 = bx * 256;
  const int kbase = bz * Ks;

  f32x16 acc[2][2];
#pragma unroll
  for (int m = 0; m < 2; ++m)
#pragma unroll
    for (int n = 0; n < 2; ++n) acc[m][n] = (f32x16)(0.f);

  const int rA = tid >> 3;        // 0..63 row within an 8KB issue
  const int cb = (tid & 7) * 16;  // byte col within 128B row
  // part p: 0 -> A issues {0,1}; 1 -> B issues {0,1}; 2 -> B issues {2,3}
  auto stage_part = [&](int buf, int k0, int p) {
    if (p == 0) {
#pragma unroll
      for (int i = 0; i < 2; ++i) {
        int r = i * 64 + rA;
        int csw = cb ^ ((r & 7) << 4);
        __builtin_amdgcn_global_load_lds(
            GPTR((const char*)(A + (size_t)(row0 + r) * Ktot + k0) + csw),
            LPTR((char*)&As[buf][0] + i * 8192 + wid * 1024), 16, 0, 0);
      }
    } else {
#pragma unroll
      for (int j2 = 0; j2 < 2; ++j2) {
        int j = (p - 1) * 2 + j2;
        int r = j * 64 + rA;
        int csw = cb ^ ((r & 7) << 4);
        __builtin_amdgcn_global_load_lds(
            GPTR((const char*)(Bt + (size_t)(col0 + r) * Ktot + k0) + csw),
            LPTR((char*)&Bs[buf][0] + j * 8192 + wid * 1024), 16, 0, 0);
      }
    }
  };
  auto stage = [&](int buf, int k0) {
    stage_part(buf, k0, 0); stage_part(buf, k0, 1); stage_part(buf, k0, 2);
  };

  const int nt = Ks / BK;  // 16
  stage(0, kbase);
  stage(1, kbase + BK);

  for (int t = 0; t < nt; ++t) {
    if (t < nt - 1) asm volatile("s_waitcnt vmcnt(6)" ::: "memory");
    else            asm volatile("s_waitcnt vmcnt(0)" ::: "memory");
    __builtin_amdgcn_sched_barrier(0);
    __builtin_amdgcn_s_barrier();   // tile t resident; buf[(t+2)%3] free
    __builtin_amdgcn_sched_barrier(0);

    const ushort* Ab = As[t % 3];
    const ushort* Bb = Bs[t % 3];
    const bool pf = (t + 2 < nt);
    const int knext = kbase + (t + 2) * BK;
    const int pbuf = (t + 2) % 3;

    bf16x8 a[2][2], b[2][2];
    auto read_slice = [&](int s, int sb) {
      const int kb2 = s * 32 + (lane >> 5) * 16;
#pragma unroll
      for (int m = 0; m < 2; ++m) {
        int R = wr * 64 + m * 32 + (lane & 31);
        a[sb][m] = *(const bf16x8*)((const char*)Ab + R * 128 + (kb2 ^ ((R & 7) << 4)));
      }
#pragma unroll
      for (int n = 0; n < 2; ++n) {
        int R = wc * 64 + n * 32 + (lane & 31);
        b[sb][n] = *(const bf16x8*)((const char*)Bb + R * 128 + (kb2 ^ ((R & 7) << 4)));
      }
    };

    read_slice(0, 0);
#pragma unroll
    for (int s = 0; s < 4; ++s) {
      if (s < 3) read_slice(s + 1, (s + 1) & 1);
      if (s < 3 && pf) stage_part(pbuf, knext, s);
      __builtin_amdgcn_s_setprio(1);
#pragma unroll
      for (int m = 0; m < 2; ++m)
#pragma unroll
        for (int n = 0; n < 2; ++n)
          acc[m][n] = __builtin_amdgcn_mfma_f32_32x32x16_bf16(a[s & 1][m], b[s & 1][n],
                                                              acc[m][n], 0, 0, 0);
      __builtin_amdgcn_s_setprio(0);
    }
  }

  // epilogue; 32x32 C/D layout (m74/m101-verified):
  //   col = lane&31, row = (r&3) + 8*(r>>2) + 4*(lane>>5)
  const int rbase = row0 + wr * 64, cbase = col0 + wc * 64;
#pragma unroll
  for (int m = 0; m < 2; ++m) {
#pragma unroll
    for (int n = 0; n < 2; ++n) {
      const int col = cbase + n * 32 + (lane & 31);
#pragma unroll
      for (int r = 0; r < 16; ++r) {
        const int row = rbase + m * 32 + (r & 3) + 8 * (r >> 2) + 4 * (lane >> 5);
        float v = acc[m][n][r];
        size_t idx = (size_t)row * N + col;
        if (MODE == 1) {
          v = v > 0.f ? v : 0.f;
          ((ushort*)C0)[idx] = f2bf(v);
        } else {
          if (bz == 0)
            ((float*)C0)[idx] = v;
          else
            C1[(size_t)(bz - 1) * M * N + idx] = f2bf(v);
        }
      }
    }
  }
}

// ---- the mega-kernel --------------------------------------------------------
__global__ __launch_bounds__(512) void moe_mega(const float* __restrict__ x,
                                                const float* __restrict__ w1,
                                                const float* __restrict__ w2,
                                                float* __restrict__ out,
                                                ushort* __restrict__ xb,
                                                ushort* __restrict__ w1t,
                                                ushort* __restrict__ w2t,
                                                ushort* __restrict__ H,
                                                ushort* __restrict__ pb) {
  constexpr int S = 2048, D = 1024, F = 4096;
  __shared__ ushort As[3][128 * 64];  // 48 KB
  __shared__ ushort Bs[3][256 * 64];  // 96 KB  (144 KB total)

  const int tid = threadIdx.x, bid = blockIdx.x;  // 256 blocks x 512 threads
  cg::grid_group grid = cg::this_grid();

  // =============== phase A: prep ===============
  {
    // x -> bf16: 524288 float4, 2048 per block, 4 per thread
#pragma unroll
    for (int j = 0; j < 4; ++j) {
      int i = bid * 2048 + j * 512 + tid;
      float4 v = ((const float4*)x)[i];
      ushort4 o;
      o.x = f2bf(v.x); o.y = f2bf(v.y); o.z = f2bf(v.z); o.w = f2bf(v.w);
      ((ushort4*)xb)[i] = o;
    }
    // transposes: 2048 64x64 tiles (1024 w1 + 1024 w2); 2 tiles per block-iter
    const int half = tid >> 8;       // 0/1 : two concurrent tiles
    const int t256 = tid & 255;
    const int tx = t256 & 15, ty = t256 >> 4;  // 16 x 16
    float (*tl)[65] = (float(*)[65])((char*)&As[0][0] + half * (64 * 65 * 4));
    for (int it = 0; it < 4; ++it) {
      int tileid = bid * 8 + it * 2 + half;  // 0..2047
      const float* in; ushort* outp; int R, C, bt;
      if (tileid < 1024) { bt = tileid;        in = w1; outp = w1t; R = 1024; C = 4096; }
      else               { bt = tileid - 1024; in = w2; outp = w2t; R = 4096; C = 1024; }
      const int ntx = C / 64;
      const int c0 = (bt % ntx) * 64, r0 = (bt / ntx) * 64;
#pragma unroll
      for (int rr = 0; rr < 64; rr += 16) {
        float4 v = *(const float4*)&in[(size_t)(r0 + ty + rr) * C + c0 + tx * 4];
        tl[ty + rr][tx * 4 + 0] = v.x;
        tl[ty + rr][tx * 4 + 1] = v.y;
        tl[ty + rr][tx * 4 + 2] = v.z;
        tl[ty + rr][tx * 4 + 3] = v.w;
      }
      __syncthreads();
#pragma unroll
      for (int cc = 0; cc < 64; cc += 16) {
        const int c = ty + cc;   // output row (= original col)
        const int r = tx * 4;    // 4 consecutive original rows
        ushort4 o;
        o.x = f2bf(tl[r + 0][c]);
        o.y = f2bf(tl[r + 1][c]);
        o.z = f2bf(tl[r + 2][c]);
        o.w = f2bf(tl[r + 3][c]);
        *(ushort4*)&outp[(size_t)(c0 + c) * R + r0 + r] = o;
      }
      __syncthreads();
    }
  }
  __threadfence();
  grid.sync();

  // =============== phase B: GEMM1  H = relu(xb @ w1t^T) ===============
  gemm_body<1>(xb, w1t, (void*)H, nullptr, S, F, D, D, 4, 8, As, Bs);
  __threadfence();
  grid.sync();

  // =============== phase C: GEMM2  out/pb = H @ w2t^T (split-K=4) ===============
  gemm_body<2>(H, w2t, (void*)out, pb, S, D, F / 4, F, 1, 2, As, Bs);
  __threadfence();
  grid.sync();

  // =============== phase D: out += pb0 + pb1 + pb2 (uniform) ===============
  {
    const int SD = S * D;
#pragma unroll
    for (int j = 0; j < 4; ++j) {
      int i = bid * 2048 + j * 512 + tid;  // f32x4 index, 524288 total
      f32x4 a = ((const f32x4*)out)[i];
#pragma unroll
      for (int z = 0; z < 3; ++z) {
        ushort4 u = ((const ushort4*)(pb + (size_t)z * SD))[i];
        a[0] += bf2f(u.x); a[1] += bf2f(u.y); a[2] += bf2f(u.z); a[3] += bf2f(u.w);
      }
      ((f32x4*)out)[i] = a;
    }
  }
}

extern "C" void kernel_launch(void* const* d_in, const int* in_sizes, int n_in,
                              void* d_out, int out_size, void* d_ws, size_t ws_size,
                              hipStream_t stream) {
  const float* x  = (const float*)d_in[0];
  // d_in[1] (Wg) is provably unused: gating collapses to identity (see header)
  const float* w1 = (const float*)d_in[2];
  const float* w2 = (const float*)d_in[3];
  float* out = (float*)d_out;

  constexpr int S = 2048, D = 1024, F = 4096;
  char* ws = (char*)d_ws;
  ushort* xb  = (ushort*)(ws);                                    // [S][D]  4 MB
  ushort* w1t = (ushort*)(ws + (size_t)S * D * 2);                // [F][D]  8 MB
  ushort* w2t = (ushort*)(ws + (size_t)(S * D + F * D) * 2);      // [D][F]  8 MB
  ushort* H   = (ushort*)(ws + (size_t)(S * D + 2 * F * D) * 2);  // [S][F] 16 MB
  // 3 bf16 split-K partials (12 MB): prefer a never-before-read region after
  // H (first-touch readers -> robust under pure release-writeback); fall back
  // to the dead xb/w1t overlay if ws is small (then relies on grid.sync's
  // agent-scope acquire invalidation, the architected behavior).
  size_t pb_hi_off = (size_t)(S * D + 2 * F * D + S * F) * 2;     // 36 MB
  ushort* pb = (ws_size >= pb_hi_off + (size_t)3 * S * D * 2)
                   ? (ushort*)(ws + pb_hi_off)
                   : (ushort*)(ws);

  void* args[] = {(void*)&x, (void*)&w1, (void*)&w2, (void*)&out,
                  (void*)&xb, (void*)&w1t, (void*)&w2t, (void*)&H, (void*)&pb};
  hipLaunchCooperativeKernel((const void*)moe_mega, dim3(256), dim3(512),
                             args, 0, stream);
}

// Round 10
// 77.259 us; speedup vs baseline: 4.2050x; 4.2050x over previous
//
#include <hip/hip_runtime.h>
#include <stdint.h>

// ============================================================================
// MoE collapses exactly to: out = relu(x @ w1) @ w2   (round-0 analysis)
//   - shared expert weights => both top-2 slots compute identical f(x[s])
//   - g1+g2 normalized to 1 => combine gather returns f(x[s])
//   - capacity = S and count1+count2 <= S => no token dropped
// Wg is unused.
//
// Round-9 -> 10: cooperative mega-kernel FALSIFIED (grid.sync ~80us each ->
// 325us). Full revert to the r7 keeper (69.8us: 128x256 tile, 256 blocks,
// 3-buffer LDS, depth-2 counted vmcnt(6), slice-level interleave, T1/T2/T5)
// plus ONE new lever: non-temporal hints on streaming traffic.
//   - GEMM epilogue stores (H / out / pb) -> nt stores: stop evicting the
//     exactly-L2-sized (4MB/XCD) A/B panel working set (FETCH 70 vs 32 MB).
//   - prep input loads (x, w1, w2) and reduce's pb/out loads -> nt loads
//     (read-once streams).
// Cache hints only; sync structure byte-identical to r7.
// ============================================================================

typedef __attribute__((ext_vector_type(4))) float f32x4;
typedef __attribute__((ext_vector_type(16))) float f32x16;
typedef __attribute__((ext_vector_type(8))) short bf16x8;
typedef __attribute__((ext_vector_type(4))) ushort u16x4;

#define GPTR(p) (const __attribute__((address_space(1))) void*)(p)
#define LPTR(p) (__attribute__((address_space(3))) void*)(p)

__device__ __forceinline__ ushort f2bf(float f) {
  uint32_t u = __float_as_uint(f);
  uint32_t r = (u + 0x7FFFu + ((u >> 16) & 1u)) >> 16;  // RNE
  return (ushort)r;
}
__device__ __forceinline__ float bf2f(ushort u) {
  return __uint_as_float((uint32_t)u << 16);
}

// ---- fused prep: x->bf16 cvt + vectorized 64x64 transposes ------------------
// grid: [0,2048) cvt x (f32x4); [2048,3072) w1 -> w1t; [3072,4096) w2 -> w2t
__global__ __launch_bounds__(256) void prep(const float* __restrict__ x,
                                            const float* __restrict__ w1,
                                            const float* __restrict__ w2,
                                            ushort* __restrict__ xb,
                                            ushort* __restrict__ w1t,
                                            ushort* __restrict__ w2t) {
  const int b = blockIdx.x, tid = threadIdx.x;
  if (b < 2048) {  // cvt: 2048 blocks x 256 th x f32x4 = 2M elems
    int i = b * 256 + tid;
    f32x4 v = __builtin_nontemporal_load(&((const f32x4*)x)[i]);
    u16x4 o;
    o.x = f2bf(v.x); o.y = f2bf(v.y); o.z = f2bf(v.z); o.w = f2bf(v.w);
    ((u16x4*)xb)[i] = o;  // consumed by GEMM1 -> keep cacheable
    return;
  }
  const float* in;
  ushort* outp;
  int R, C, bt;
  if (b < 3072) { bt = b - 2048; in = w1; outp = w1t; R = 1024; C = 4096; }
  else          { bt = b - 3072; in = w2; outp = w2t; R = 4096; C = 1024; }
  const int ntx = C / 64;
  const int bx = bt % ntx, by = bt / ntx;
  const int c0 = bx * 64, r0 = by * 64;
  __shared__ float tile[64][65];
  const int tx = tid & 15, ty = tid >> 4;  // 16 x 16
#pragma unroll
  for (int rr = 0; rr < 64; rr += 16) {
    f32x4 v = __builtin_nontemporal_load(
        (const f32x4*)&in[(size_t)(r0 + ty + rr) * C + c0 + tx * 4]);
    tile[ty + rr][tx * 4 + 0] = v.x;
    tile[ty + rr][tx * 4 + 1] = v.y;
    tile[ty + rr][tx * 4 + 2] = v.z;
    tile[ty + rr][tx * 4 + 3] = v.w;
  }
  __syncthreads();
#pragma unroll
  for (int cc = 0; cc < 64; cc += 16) {
    const int c = ty + cc;   // output row (= original col)
    const int r = tx * 4;    // 4 consecutive original rows
    u16x4 o;
    o.x = f2bf(tile[r + 0][c]);
    o.y = f2bf(tile[r + 1][c]);
    o.z = f2bf(tile[r + 2][c]);
    o.w = f2bf(tile[r + 3][c]);
    *(u16x4*)&outp[(size_t)(c0 + c) * R + r0 + r] = o;  // cacheable
  }
}

// ---- out += sum of 3 bf16 partials (streaming, nt loads) --------------------
__global__ void reduce_out(float* __restrict__ out, const ushort* __restrict__ pb,
                           int SD) {
  int i = blockIdx.x * blockDim.x + threadIdx.x;  // 4 floats / thread
  if (i >= SD / 4) return;
  f32x4 a = __builtin_nontemporal_load(&((const f32x4*)out)[i]);
#pragma unroll
  for (int j = 0; j < 3; ++j) {
    u16x4 u = __builtin_nontemporal_load(&((const u16x4*)(pb + (size_t)j * SD))[i]);
    a[0] += bf2f(u.x); a[1] += bf2f(u.y); a[2] += bf2f(u.z); a[3] += bf2f(u.w);
  }
  __builtin_nontemporal_store(a, &((f32x4*)out)[i]);
}

// ---- bf16 GEMM, B transposed ([N][K]); counted-vmcnt + fine interleave ------
// MODE 1: C0 = relu(A@Bt^T) as bf16.  MODE 2: split-K; bz==0 -> fp32 C0,
// bz>0 -> bf16 partial C1 + (bz-1)*M*N.
// BM=128 x BN=256 x BK=64, 8 waves (2x4), per-wave 64x64 (2x2 32x32 frags).
// 3-buffer LDS (144 KB), depth-2 prefetch, steady-state s_waitcnt vmcnt(6),
// ONE barrier per K-step. K-step = 4 k-slices, software-pipelined:
// read slice s+1 (4 ds_read_b128) + 2 stage loads, then 4 MFMAs of slice s.
template <int MODE>
__global__ __launch_bounds__(512) void gemm_pipe(const ushort* __restrict__ A,
                                                 const ushort* __restrict__ Bt,
                                                 void* __restrict__ C0,
                                                 void* __restrict__ C1,
                                                 int M, int N, int Ks, int Ktot,
                                                 int ncx, int cpz) {
  constexpr int BM = 128, BN = 256, BK = 64;
  __shared__ ushort As[3][BM * BK];  // 3 x 16 KB
  __shared__ ushort Bs[3][BN * BK];  // 3 x 32 KB   (total 144 KB)

  const int tid = threadIdx.x;
  const int lane = tid & 63, wid = tid >> 6;  // 8 waves
  const int wr = wid >> 2, wc = wid & 3;      // 2 x 4 wave grid

  // T1 (2D-chunked): chunk (=XCD) = blockIdx.x & 7, 32 blocks/chunk -> 4x8.
  const int ck = blockIdx.x & 7;
  const int w = blockIdx.x >> 3;
  const int bz = ck / cpz;
  const int rem = ck % cpz;
  const int bx = (rem % ncx) * 4 + (w & 3);
  const int by = (rem / ncx) * 8 + (w >> 2);
  const int row0 = by * BM, col0 = bx * BN;
  const int kbase = bz * Ks;

  f32x16 acc[2][2];
#pragma unroll
  for (int m = 0; m < 2; ++m)
#pragma unroll
    for (int n = 0; n < 2; ++n) acc[m][n] = (f32x16)(0.f);

  // staging: 6 global_load_lds x 16B per thread (A 2 issues + B 4 issues).
  // LDS dest LINEAR; source col XOR-swizzled (rule #21, verified r4-r8).
  const int rA = tid >> 3;        // 0..63 row within an 8KB issue
  const int cb = (tid & 7) * 16;  // byte col within 128B row
  // part p: 0 -> A issues {0,1}; 1 -> B issues {0,1}; 2 -> B issues {2,3}
  auto stage_part = [&](int buf, int k0, int p) {
    if (p == 0) {
#pragma unroll
      for (int i = 0; i < 2; ++i) {
        int r = i * 64 + rA;
        int csw = cb ^ ((r & 7) << 4);
        __builtin_amdgcn_global_load_lds(
            GPTR((const char*)(A + (size_t)(row0 + r) * Ktot + k0) + csw),
            LPTR((char*)&As[buf][0] + i * 8192 + wid * 1024), 16, 0, 0);
      }
    } else {
#pragma unroll
      for (int j2 = 0; j2 < 2; ++j2) {
        int j = (p - 1) * 2 + j2;
        int r = j * 64 + rA;
        int csw = cb ^ ((r & 7) << 4);
        __builtin_amdgcn_global_load_lds(
            GPTR((const char*)(Bt + (size_t)(col0 + r) * Ktot + k0) + csw),
            LPTR((char*)&Bs[buf][0] + j * 8192 + wid * 1024), 16, 0, 0);
      }
    }
  };
  auto stage = [&](int buf, int k0) {
    stage_part(buf, k0, 0); stage_part(buf, k0, 1); stage_part(buf, k0, 2);
  };

  const int nt = Ks / BK;  // 16 for both GEMMs
  stage(0, kbase);
  stage(1, kbase + BK);

  for (int t = 0; t < nt; ++t) {
    // own tile-t loads landed; tile t+1's 6 stay in flight across the barrier
    if (t < nt - 1) asm volatile("s_waitcnt vmcnt(6)" ::: "memory");
    else            asm volatile("s_waitcnt vmcnt(0)" ::: "memory");
    __builtin_amdgcn_sched_barrier(0);
    __builtin_amdgcn_s_barrier();   // all waves: tile-t resident, buf[(t+2)%3]
                                    // free (its readers finished at step t-1)
    __builtin_amdgcn_sched_barrier(0);

    const ushort* Ab = As[t % 3];
    const ushort* Bb = Bs[t % 3];
    const bool pf = (t + 2 < nt);
    const int knext = kbase + (t + 2) * BK;
    const int pbuf = (t + 2) % 3;

    // 2-slice register pipeline: read s+1 while MFMA s (static idx, rule #20)
    bf16x8 a[2][2], b[2][2];
    auto read_slice = [&](int s, int sb) {
      const int kb2 = s * 32 + (lane >> 5) * 16;
#pragma unroll
      for (int m = 0; m < 2; ++m) {
        int R = wr * 64 + m * 32 + (lane & 31);
        a[sb][m] = *(const bf16x8*)((const char*)Ab + R * 128 + (kb2 ^ ((R & 7) << 4)));
      }
#pragma unroll
      for (int n = 0; n < 2; ++n) {
        int R = wc * 64 + n * 32 + (lane & 31);
        b[sb][n] = *(const bf16x8*)((const char*)Bb + R * 128 + (kb2 ^ ((R & 7) << 4)));
      }
    };

    read_slice(0, 0);
#pragma unroll
    for (int s = 0; s < 4; ++s) {
      if (s < 3) read_slice(s + 1, (s + 1) & 1);   // reads fly over MFMAs below
      if (s < 3 && pf) stage_part(pbuf, knext, s); // spread VMEM issue (m196)
      __builtin_amdgcn_s_setprio(1);
#pragma unroll
      for (int m = 0; m < 2; ++m)
#pragma unroll
        for (int n = 0; n < 2; ++n)
          acc[m][n] = __builtin_amdgcn_mfma_f32_32x32x16_bf16(a[s & 1][m], b[s & 1][n],
                                                              acc[m][n], 0, 0, 0);
      __builtin_amdgcn_s_setprio(0);
    }
  }

  // epilogue; 32x32 C/D layout (m74/m101-verified):
  //   col = lane&31, row = (r&3) + 8*(r>>2) + 4*(lane>>5)
  // All outputs are streaming (read by LATER kernels, not this one) ->
  // non-temporal stores keep the K-loop panel working set resident in L2.
  const int rbase = row0 + wr * 64, cbase = col0 + wc * 64;
#pragma unroll
  for (int m = 0; m < 2; ++m) {
#pragma unroll
    for (int n = 0; n < 2; ++n) {
      const int col = cbase + n * 32 + (lane & 31);
#pragma unroll
      for (int r = 0; r < 16; ++r) {
        const int row = rbase + m * 32 + (r & 3) + 8 * (r >> 2) + 4 * (lane >> 5);
        float v = acc[m][n][r];
        size_t idx = (size_t)row * N + col;
        if (MODE == 1) {
          v = v > 0.f ? v : 0.f;
          __builtin_nontemporal_store(f2bf(v), &((ushort*)C0)[idx]);
        } else {
          if (bz == 0)
            __builtin_nontemporal_store(v, &((float*)C0)[idx]);
          else
            __builtin_nontemporal_store(f2bf(v),
                &((ushort*)C1)[(size_t)(bz - 1) * M * N + idx]);
        }
      }
    }
  }
}

extern "C" void kernel_launch(void* const* d_in, const int* in_sizes, int n_in,
                              void* d_out, int out_size, void* d_ws, size_t ws_size,
                              hipStream_t stream) {
  const float* x  = (const float*)d_in[0];
  // d_in[1] (Wg) is provably unused: gating collapses to identity (see header)
  const float* w1 = (const float*)d_in[2];
  const float* w2 = (const float*)d_in[3];
  float* out = (float*)d_out;

  constexpr int S = 2048, D = 1024, F = 4096;
  char* ws = (char*)d_ws;
  ushort* xb  = (ushort*)(ws);                                    // [S][D]  4 MB
  ushort* w1t = (ushort*)(ws + (size_t)S * D * 2);                // [F][D]  8 MB
  ushort* w2t = (ushort*)(ws + (size_t)(S * D + F * D) * 2);      // [D][F]  8 MB
  ushort* H   = (ushort*)(ws + (size_t)(S * D + 2 * F * D) * 2);  // [S][F] 16 MB
  // 3 bf16 split-K partials (12 MB) overlay xb+w1t (dead after GEMM1).
  ushort* pb = (ushort*)(ws);

  // fused prep: 2048 cvt + 1024 w1-transpose + 1024 w2-transpose (64x64 tiles)
  hipLaunchKernelGGL(prep, dim3(4096), dim3(256), 0, stream,
                     x, w1, w2, xb, w1t, w2t);
  // GEMM1: H = relu(xb @ w1t^T)  [2048 x 4096], K=1024
  //   grid 16x16 = 256; chunks: ncx=4, cpz=8 (nz=1)
  hipLaunchKernelGGL((gemm_pipe<1>), dim3(256), dim3(512), 0, stream,
                     xb, w1t, (void*)H, nullptr, S, F, D, D, 4, 8);
  // GEMM2: out = H @ w2t^T  [2048 x 1024], K=4096 split 4x1024
  //   grid 4x16x4 = 256; chunks: ncx=1, cpz=2 (nz=4)
  hipLaunchKernelGGL((gemm_pipe<2>), dim3(256), dim3(512), 0, stream,
                     H, w2t, (void*)out, (void*)pb, S, D, F / 4, F, 1, 2);
  // out += p1 + p2 + p3
  hipLaunchKernelGGL(reduce_out, dim3((S * D / 4 + 255) / 256), dim3(256), 0, stream,
                     out, pb, S * D);
}

// Round 11
// 68.757 us; speedup vs baseline: 4.7250x; 1.1237x over previous
//
#include <hip/hip_runtime.h>
#include <stdint.h>

// ============================================================================
// MoE collapses exactly to: out = relu(x @ w1) @ w2   (round-0 analysis)
//   - shared expert weights => both top-2 slots compute identical f(x[s])
//   - g1+g2 normalized to 1 => combine gather returns f(x[s])
//   - capacity = S and count1+count2 <= S => no token dropped
// Wg is unused.
//
// Round-10 -> 11: nt hints FALSIFIED (-7.5us: H/out/pb are producer->consumer
// buffers; nt stores killed their L2 residency for the NEXT kernel). Full
// revert to r7 (69.8us keeper). Two small deltas:
//  1) big-ws path: 4 bf16 split-K partials in the untouched region above H;
//     reduce reads 16MB + writes 8MB (was 36MB total)  (~-2us)
//  2) s_setprio removed (m190: slightly negative on barrier-synced GEMMs)
// ============================================================================

typedef __attribute__((ext_vector_type(4))) float f32x4;
typedef __attribute__((ext_vector_type(16))) float f32x16;
typedef __attribute__((ext_vector_type(8))) short bf16x8;
typedef __attribute__((ext_vector_type(4))) ushort u16x4;

#define GPTR(p) (const __attribute__((address_space(1))) void*)(p)
#define LPTR(p) (__attribute__((address_space(3))) void*)(p)

__device__ __forceinline__ ushort f2bf(float f) {
  uint32_t u = __float_as_uint(f);
  uint32_t r = (u + 0x7FFFu + ((u >> 16) & 1u)) >> 16;  // RNE
  return (ushort)r;
}
__device__ __forceinline__ float bf2f(ushort u) {
  return __uint_as_float((uint32_t)u << 16);
}

// ---- fused prep: x->bf16 cvt + vectorized 64x64 transposes ------------------
// grid: [0,2048) cvt x (f32x4); [2048,3072) w1 -> w1t; [3072,4096) w2 -> w2t
__global__ __launch_bounds__(256) void prep(const float* __restrict__ x,
                                            const float* __restrict__ w1,
                                            const float* __restrict__ w2,
                                            ushort* __restrict__ xb,
                                            ushort* __restrict__ w1t,
                                            ushort* __restrict__ w2t) {
  const int b = blockIdx.x, tid = threadIdx.x;
  if (b < 2048) {  // cvt: 2048 blocks x 256 th x f32x4 = 2M elems
    int i = b * 256 + tid;
    f32x4 v = ((const f32x4*)x)[i];
    u16x4 o;
    o.x = f2bf(v.x); o.y = f2bf(v.y); o.z = f2bf(v.z); o.w = f2bf(v.w);
    ((u16x4*)xb)[i] = o;
    return;
  }
  const float* in;
  ushort* outp;
  int R, C, bt;
  if (b < 3072) { bt = b - 2048; in = w1; outp = w1t; R = 1024; C = 4096; }
  else          { bt = b - 3072; in = w2; outp = w2t; R = 4096; C = 1024; }
  const int ntx = C / 64;
  const int bx = bt % ntx, by = bt / ntx;
  const int c0 = bx * 64, r0 = by * 64;
  __shared__ float tile[64][65];
  const int tx = tid & 15, ty = tid >> 4;  // 16 x 16
#pragma unroll
  for (int rr = 0; rr < 64; rr += 16) {
    f32x4 v = *(const f32x4*)&in[(size_t)(r0 + ty + rr) * C + c0 + tx * 4];
    tile[ty + rr][tx * 4 + 0] = v.x;
    tile[ty + rr][tx * 4 + 1] = v.y;
    tile[ty + rr][tx * 4 + 2] = v.z;
    tile[ty + rr][tx * 4 + 3] = v.w;
  }
  __syncthreads();
#pragma unroll
  for (int cc = 0; cc < 64; cc += 16) {
    const int c = ty + cc;   // output row (= original col)
    const int r = tx * 4;    // 4 consecutive original rows
    u16x4 o;
    o.x = f2bf(tile[r + 0][c]);
    o.y = f2bf(tile[r + 1][c]);
    o.z = f2bf(tile[r + 2][c]);
    o.w = f2bf(tile[r + 3][c]);
    *(u16x4*)&outp[(size_t)(c0 + c) * R + r0 + r] = o;
  }
}

// ---- reduce: MODE4: out = pb0+pb1+pb2+pb3 (no out read); MODE3: out += 3 pb -
__global__ void reduce_out(float* __restrict__ out, const ushort* __restrict__ pb,
                           int SD, int nparts) {
  int i = blockIdx.x * blockDim.x + threadIdx.x;  // 4 floats / thread
  if (i >= SD / 4) return;
  f32x4 a;
  if (nparts == 4) a = (f32x4){0.f, 0.f, 0.f, 0.f};
  else             a = ((const f32x4*)out)[i];
  for (int j = 0; j < nparts; ++j) {
    u16x4 u = ((const u16x4*)(pb + (size_t)j * SD))[i];
    a[0] += bf2f(u.x); a[1] += bf2f(u.y); a[2] += bf2f(u.z); a[3] += bf2f(u.w);
  }
  ((f32x4*)out)[i] = a;
}

// ---- bf16 GEMM, B transposed ([N][K]); counted-vmcnt + fine interleave ------
// MODE 1: C0 = relu(A@Bt^T) as bf16.
// MODE 2: split-K over bz; z0p=1 -> ALL z write bf16 partial C1 + bz*M*N;
//         z0p=0 -> bz==0 fp32 C0, bz>0 bf16 partial C1 + (bz-1)*M*N.
// BM=128 x BN=256 x BK=64, 8 waves (2x4), per-wave 64x64 (2x2 32x32 frags).
// 3-buffer LDS (144 KB), depth-2 prefetch, steady-state s_waitcnt vmcnt(6),
// ONE barrier per K-step. K-step = 4 k-slices, software-pipelined:
// read slice s+1 (4 ds_read_b128) + 2 stage loads, then 4 MFMAs of slice s.
template <int MODE>
__global__ __launch_bounds__(512) void gemm_pipe(const ushort* __restrict__ A,
                                                 const ushort* __restrict__ Bt,
                                                 void* __restrict__ C0,
                                                 ushort* __restrict__ C1,
                                                 int M, int N, int Ks, int Ktot,
                                                 int ncx, int cpz, int z0p) {
  constexpr int BM = 128, BN = 256, BK = 64;
  __shared__ ushort As[3][BM * BK];  // 3 x 16 KB
  __shared__ ushort Bs[3][BN * BK];  // 3 x 32 KB   (total 144 KB)

  const int tid = threadIdx.x;
  const int lane = tid & 63, wid = tid >> 6;  // 8 waves
  const int wr = wid >> 2, wc = wid & 3;      // 2 x 4 wave grid

  // T1 (2D-chunked): chunk (=XCD) = blockIdx.x & 7, 32 blocks/chunk -> 4x8.
  const int ck = blockIdx.x & 7;
  const int w = blockIdx.x >> 3;
  const int bz = ck / cpz;
  const int rem = ck % cpz;
  const int bx = (rem % ncx) * 4 + (w & 3);
  const int by = (rem / ncx) * 8 + (w >> 2);
  const int row0 = by * BM, col0 = bx * BN;
  const int kbase = bz * Ks;

  f32x16 acc[2][2];
#pragma unroll
  for (int m = 0; m < 2; ++m)
#pragma unroll
    for (int n = 0; n < 2; ++n) acc[m][n] = (f32x16)(0.f);

  // staging: 6 global_load_lds x 16B per thread (A 2 issues + B 4 issues).
  // LDS dest LINEAR; source col XOR-swizzled (rule #21, verified r4-r10).
  const int rA = tid >> 3;        // 0..63 row within an 8KB issue
  const int cb = (tid & 7) * 16;  // byte col within 128B row
  // part p: 0 -> A issues {0,1}; 1 -> B issues {0,1}; 2 -> B issues {2,3}
  auto stage_part = [&](int buf, int k0, int p) {
    if (p == 0) {
#pragma unroll
      for (int i = 0; i < 2; ++i) {
        int r = i * 64 + rA;
        int csw = cb ^ ((r & 7) << 4);
        __builtin_amdgcn_global_load_lds(
            GPTR((const char*)(A + (size_t)(row0 + r) * Ktot + k0) + csw),
            LPTR((char*)&As[buf][0] + i * 8192 + wid * 1024), 16, 0, 0);
      }
    } else {
#pragma unroll
      for (int j2 = 0; j2 < 2; ++j2) {
        int j = (p - 1) * 2 + j2;
        int r = j * 64 + rA;
        int csw = cb ^ ((r & 7) << 4);
        __builtin_amdgcn_global_load_lds(
            GPTR((const char*)(Bt + (size_t)(col0 + r) * Ktot + k0) + csw),
            LPTR((char*)&Bs[buf][0] + j * 8192 + wid * 1024), 16, 0, 0);
      }
    }
  };
  auto stage = [&](int buf, int k0) {
    stage_part(buf, k0, 0); stage_part(buf, k0, 1); stage_part(buf, k0, 2);
  };

  const int nt = Ks / BK;  // 16 for both GEMMs
  stage(0, kbase);
  stage(1, kbase + BK);

  for (int t = 0; t < nt; ++t) {
    // own tile-t loads landed; tile t+1's 6 stay in flight across the barrier
    if (t < nt - 1) asm volatile("s_waitcnt vmcnt(6)" ::: "memory");
    else            asm volatile("s_waitcnt vmcnt(0)" ::: "memory");
    __builtin_amdgcn_sched_barrier(0);
    __builtin_amdgcn_s_barrier();   // all waves: tile-t resident, buf[(t+2)%3]
                                    // free (its readers finished at step t-1)
    __builtin_amdgcn_sched_barrier(0);

    const ushort* Ab = As[t % 3];
    const ushort* Bb = Bs[t % 3];
    const bool pf = (t + 2 < nt);
    const int knext = kbase + (t + 2) * BK;
    const int pbuf = (t + 2) % 3;

    // 2-slice register pipeline: read s+1 while MFMA s (static idx, rule #20)
    bf16x8 a[2][2], b[2][2];
    auto read_slice = [&](int s, int sb) {
      const int kb2 = s * 32 + (lane >> 5) * 16;
#pragma unroll
      for (int m = 0; m < 2; ++m) {
        int R = wr * 64 + m * 32 + (lane & 31);
        a[sb][m] = *(const bf16x8*)((const char*)Ab + R * 128 + (kb2 ^ ((R & 7) << 4)));
      }
#pragma unroll
      for (int n = 0; n < 2; ++n) {
        int R = wc * 64 + n * 32 + (lane & 31);
        b[sb][n] = *(const bf16x8*)((const char*)Bb + R * 128 + (kb2 ^ ((R & 7) << 4)));
      }
    };

    read_slice(0, 0);
#pragma unroll
    for (int s = 0; s < 4; ++s) {
      if (s < 3) read_slice(s + 1, (s + 1) & 1);   // reads fly over MFMAs below
      if (s < 3 && pf) stage_part(pbuf, knext, s); // spread VMEM issue (m196)
#pragma unroll
      for (int m = 0; m < 2; ++m)
#pragma unroll
        for (int n = 0; n < 2; ++n)
          acc[m][n] = __builtin_amdgcn_mfma_f32_32x32x16_bf16(a[s & 1][m], b[s & 1][n],
                                                              acc[m][n], 0, 0, 0);
    }
  }

  // epilogue; 32x32 C/D layout (m74/m101-verified):
  //   col = lane&31, row = (r&3) + 8*(r>>2) + 4*(lane>>5)
  const int rbase = row0 + wr * 64, cbase = col0 + wc * 64;
#pragma unroll
  for (int m = 0; m < 2; ++m) {
#pragma unroll
    for (int n = 0; n < 2; ++n) {
      const int col = cbase + n * 32 + (lane & 31);
#pragma unroll
      for (int r = 0; r < 16; ++r) {
        const int row = rbase + m * 32 + (r & 3) + 8 * (r >> 2) + 4 * (lane >> 5);
        float v = acc[m][n][r];
        size_t idx = (size_t)row * N + col;
        if (MODE == 1) {
          v = v > 0.f ? v : 0.f;
          ((ushort*)C0)[idx] = f2bf(v);
        } else {
          if (z0p)
            C1[(size_t)bz * M * N + idx] = f2bf(v);
          else if (bz == 0)
            ((float*)C0)[idx] = v;
          else
            C1[(size_t)(bz - 1) * M * N + idx] = f2bf(v);
        }
      }
    }
  }
}

extern "C" void kernel_launch(void* const* d_in, const int* in_sizes, int n_in,
                              void* d_out, int out_size, void* d_ws, size_t ws_size,
                              hipStream_t stream) {
  const float* x  = (const float*)d_in[0];
  // d_in[1] (Wg) is provably unused: gating collapses to identity (see header)
  const float* w1 = (const float*)d_in[2];
  const float* w2 = (const float*)d_in[3];
  float* out = (float*)d_out;

  constexpr int S = 2048, D = 1024, F = 4096;
  char* ws = (char*)d_ws;
  ushort* xb  = (ushort*)(ws);                                    // [S][D]  4 MB
  ushort* w1t = (ushort*)(ws + (size_t)S * D * 2);                // [F][D]  8 MB
  ushort* w2t = (ushort*)(ws + (size_t)(S * D + F * D) * 2);      // [D][F]  8 MB
  ushort* H   = (ushort*)(ws + (size_t)(S * D + 2 * F * D) * 2);  // [S][F] 16 MB

  // split-K partials: big-ws path = 4 bf16 partials in the untouched region
  // above H (z0 also writes a partial; reduce never reads out). Fallback =
  // r7 path: 3 partials overlaying dead xb/w1t, z0 writes fp32 to out.
  const size_t hi_off = (size_t)(S * D + 2 * F * D + S * F) * 2;  // 36 MB
  const bool big = ws_size >= hi_off + (size_t)4 * S * D * 2;     // +16 MB
  ushort* pb = big ? (ushort*)(ws + hi_off) : (ushort*)(ws);
  const int z0p = big ? 1 : 0;
  const int nparts = big ? 4 : 3;

  // fused prep: 2048 cvt + 1024 w1-transpose + 1024 w2-transpose (64x64 tiles)
  hipLaunchKernelGGL(prep, dim3(4096), dim3(256), 0, stream,
                     x, w1, w2, xb, w1t, w2t);
  // GEMM1: H = relu(xb @ w1t^T)  [2048 x 4096], K=1024
  //   grid 16x16 = 256; chunks: ncx=4, cpz=8 (nz=1)
  hipLaunchKernelGGL((gemm_pipe<1>), dim3(256), dim3(512), 0, stream,
                     xb, w1t, (void*)H, (ushort*)nullptr, S, F, D, D, 4, 8, 0);
  // GEMM2: out = H @ w2t^T  [2048 x 1024], K=4096 split 4x1024
  //   grid 4x16x4 = 256; chunks: ncx=1, cpz=2 (nz=4)
  hipLaunchKernelGGL((gemm_pipe<2>), dim3(256), dim3(512), 0, stream,
                     H, w2t, (void*)out, pb, S, D, F / 4, F, 1, 2, z0p);
  // out = (sum of 4 partials)  |  out += 3 partials
  hipLaunchKernelGGL(reduce_out, dim3((S * D / 4 + 255) / 256), dim3(256), 0, stream,
                     out, pb, S * D, nparts);
}